// Round 3
// baseline (204.247 us; speedup 1.0000x reference)
//
#include <hip/hip_runtime.h>
#include <hip/hip_bf16.h>

// RelationNet fused pipeline, fp32 in/out, split-bf16 MFMA internal.
// B=4 Q=256 S=128 C=256; feats 512 -> 256 -> 64 -> 1; BN (training stats) + ReLU each layer.
//
// Factorization: concat(uq,us) @ W0^T = query@W0a^T + support@W0b^T
//   => Aq[b,q,o], As[b,s,o] (b0 folded into As). BN0 stats analytic:
//   sum  y0 = S*sum(Aq) + Q*sum(As)
//   sum y0^2 = S*sum(Aq^2) + Q*sum(As^2) + 2*sum_b (sum_q Aq[b])·(sum_s As[b])
// fp32 accuracy on matrix cores via hi/lo bf16 split: a·b ≈ ah·bh + al·bh + ah·bl.

typedef __attribute__((ext_vector_type(4))) float f32x4;
typedef __attribute__((ext_vector_type(8))) short s16x8;
typedef __attribute__((ext_vector_type(4))) short s16x4;

#define BN_EPS 1e-5f
#define INV_N  (1.0f/131072.0f)

// returns (hi << 16) | lo  — each a truncated bf16 pattern
__device__ __forceinline__ unsigned splitbf(float v) {
  unsigned u = __float_as_uint(v);
  unsigned hi = u >> 16;
  float r = v - __uint_as_float(u & 0xFFFF0000u);
  unsigned lo = __float_as_uint(r) >> 16;
  return (hi << 16) | lo;
}

// ---------------------------------------------------------------------------
// K0: pre-split W0 [256,512] and W1 [64,256] into hi/lo bf16 arrays.
// grid 576x256: blocks 0..511 -> W0, 512..575 -> W1.
// ---------------------------------------------------------------------------
__global__ __launch_bounds__(256) void k_prep(
    const float* __restrict__ W0, const float* __restrict__ W1,
    ushort* __restrict__ W0h, ushort* __restrict__ W0l,
    ushort* __restrict__ W1h, ushort* __restrict__ W1l)
{
  int bi = blockIdx.x;
  const float* src; ushort *dh, *dl; int idx;
  if (bi < 512) { src = W0; dh = W0h; dl = W0l; idx = bi * 256 + threadIdx.x; }
  else          { src = W1; dh = W1h; dl = W1l; idx = (bi - 512) * 256 + threadIdx.x; }
  unsigned p = splitbf(src[idx]);
  dh[idx] = (ushort)(p >> 16); dl[idx] = (ushort)(p & 0xFFFFu);
}

// ---------------------------------------------------------------------------
// K1: Aq = query @ W0[:, :256]^T ; As = support @ W0[:, 256:]^T + b0
// MFMA 16x16x32 bf16, 3-term split. 96 blocks x 64 threads (1 wave = 64x64 tile).
// blocks 0..63: Aq (M=1024); 64..95: As (M=512).
// ---------------------------------------------------------------------------
__global__ __launch_bounds__(64) void k_gemm0(
    const float* __restrict__ Qf, const float* __restrict__ Sf,
    const ushort* __restrict__ W0h, const ushort* __restrict__ W0l,
    const float* __restrict__ b0, float* __restrict__ Aq, float* __restrict__ As)
{
  int bi = blockIdx.x;
  int l = threadIdx.x, l15 = l & 15, quad = l >> 4;
  bool isQ = (bi < 64);
  const float* X;
  float* Out;
  int mtile, ntile, koff;
  if (isQ) { mtile = bi >> 2; ntile = bi & 3; X = Qf; Out = Aq; koff = 0; }
  else     { int b2i = bi - 64; mtile = b2i >> 2; ntile = b2i & 3; X = Sf; Out = As; koff = 256; }
  int m0 = mtile * 64, n0 = ntile * 64;

  f32x4 acc[4][4] = {};
#pragma unroll
  for (int ko = 0; ko < 256; ko += 32) {
    s16x8 ah[4], al[4], bh[4], bl[4];
#pragma unroll
    for (int mt = 0; mt < 4; mt++) {
      const float* row = X + (m0 + mt * 16 + l15) * 256 + ko + quad * 8;
      f32x4 v0 = *(const f32x4*)(row);
      f32x4 v1 = *(const f32x4*)(row + 4);
      s16x8 h, lo;
#pragma unroll
      for (int u = 0; u < 4; u++) {
        unsigned p0 = splitbf(v0[u]);
        h[u] = (short)(p0 >> 16); lo[u] = (short)(p0 & 0xFFFFu);
        unsigned p1 = splitbf(v1[u]);
        h[4 + u] = (short)(p1 >> 16); lo[4 + u] = (short)(p1 & 0xFFFFu);
      }
      ah[mt] = h; al[mt] = lo;
    }
#pragma unroll
    for (int nt = 0; nt < 4; nt++) {
      int off = (n0 + nt * 16 + l15) * 512 + koff + ko + quad * 8;
      bh[nt] = *(const s16x8*)(W0h + off);
      bl[nt] = *(const s16x8*)(W0l + off);
    }
#pragma unroll
    for (int mt = 0; mt < 4; mt++)
#pragma unroll
      for (int nt = 0; nt < 4; nt++) {
        acc[mt][nt] = __builtin_amdgcn_mfma_f32_16x16x32_bf16(ah[mt], bh[nt], acc[mt][nt], 0, 0, 0);
        acc[mt][nt] = __builtin_amdgcn_mfma_f32_16x16x32_bf16(al[mt], bh[nt], acc[mt][nt], 0, 0, 0);
        acc[mt][nt] = __builtin_amdgcn_mfma_f32_16x16x32_bf16(ah[mt], bl[nt], acc[mt][nt], 0, 0, 0);
      }
  }
  // D layout: col = lane&15 (n), row = quad*4 + r (m)
#pragma unroll
  for (int nt = 0; nt < 4; nt++) {
    int o = n0 + nt * 16 + l15;
    float bias = isQ ? 0.0f : b0[o];
#pragma unroll
    for (int mt = 0; mt < 4; mt++) {
      int row = m0 + mt * 16 + quad * 4;
#pragma unroll
      for (int r = 0; r < 4; r++)
        Out[(row + r) * 256 + o] = acc[mt][nt][r] + bias;
    }
  }
}

// ---------------------------------------------------------------------------
// K2: per-(b,chunk) partial sums for BN0 stats. 16 blocks x 256 thr.
// ws0p: [0:4096) sumAq, [4096:8192) sumAq2, [8192:12288) sumAs, [12288:16384) sumAs2
// ---------------------------------------------------------------------------
__global__ __launch_bounds__(256) void k_stats0(
    const float* __restrict__ Aq, const float* __restrict__ As, float* __restrict__ ws0p)
{
  int b = blockIdx.x >> 2, ch = blockIdx.x & 3;
  int o = threadIdx.x;
  float sq1 = 0, sq2 = 0, ss1 = 0, ss2 = 0;
#pragma unroll 4
  for (int q = ch * 64; q < ch * 64 + 64; q++) {
    float v = Aq[((b << 8) + q) * 256 + o]; sq1 += v; sq2 += v * v;
  }
#pragma unroll 4
  for (int s = ch * 32; s < ch * 32 + 32; s++) {
    float v = As[((b << 7) + s) * 256 + o]; ss1 += v; ss2 += v * v;
  }
  int idx = (b * 4 + ch) * 256 + o;
  ws0p[idx] = sq1; ws0p[4096 + idx] = sq2; ws0p[8192 + idx] = ss1; ws0p[12288 + idx] = ss2;
}

// ---------------------------------------------------------------------------
// K3: finalize BN0 -> a0[256], c0[256]  (z0 = relu(a0*(Aq+As) + c0))
// ---------------------------------------------------------------------------
__global__ __launch_bounds__(256) void k_fin0(
    const float* __restrict__ ws0p, const float* __restrict__ g0,
    const float* __restrict__ bt0, float* __restrict__ a0c0)
{
  int o = threadIdx.x;
  float SQ1[4], SS1[4], SQ2 = 0, SS2 = 0;
#pragma unroll
  for (int b = 0; b < 4; b++) {
    float s = 0, t = 0;
#pragma unroll
    for (int ch = 0; ch < 4; ch++) {
      int idx = (b * 4 + ch) * 256 + o;
      s += ws0p[idx]; SQ2 += ws0p[4096 + idx];
      t += ws0p[8192 + idx]; SS2 += ws0p[12288 + idx];
    }
    SQ1[b] = s; SS1[b] = t;
  }
  float sumY = 0, cross = 0;
#pragma unroll
  for (int b = 0; b < 4; b++) { sumY += 128.0f * SQ1[b] + 256.0f * SS1[b]; cross += SQ1[b] * SS1[b]; }
  float mean = sumY * INV_N;
  float sumY2 = 128.0f * SQ2 + 256.0f * SS2 + 2.0f * cross;
  float var = sumY2 * INV_N - mean * mean;
  float a = g0[o] * rsqrtf(var + BN_EPS);
  a0c0[o] = a;
  a0c0[256 + o] = bt0[o] - mean * a;
}

// ---------------------------------------------------------------------------
// K4/K6: main GEMM, two passes over identical compute (recompute beats storing
// 32 MB of y1). Per (b, qtile, stile): z0 generated in A-frag layout in regs,
// y1[256 pairs][64 j] = z0 @ W1^T + b1 via 3-term split MFMA.
// PASS2=false: BN1 partial stats -> ws1p[bi][0:64)=sum,[64:128)=sumsq.
// PASS2=true : z1=relu(a1*y1+c1); y2 = z1@W2 + b2 (shuffle over 16 j-lanes),
//              y2 stored at true (b,q,s) order + BN2 partials ws2p.
// Mapping: q = qt*16 + w*4 + mt ; A-frag m(lane&15) = s-in-tile ; k = channel.
// D: col(lane&15) = j-in-tile, row(quad*4+r) = s-in-tile.
// ---------------------------------------------------------------------------
template<bool PASS2>
__global__ __launch_bounds__(256) void k_main_t(
    const float* __restrict__ Aq, const float* __restrict__ As,
    const float* __restrict__ a0c0,
    const ushort* __restrict__ W1h, const ushort* __restrict__ W1l,
    const float* __restrict__ b1, float* __restrict__ ws1p,
    const float* __restrict__ a1c1, const float* __restrict__ W2,
    const float* __restrict__ b2, float* __restrict__ y2, float* __restrict__ ws2p)
{
  int bi = blockIdx.x;
  int b = bi >> 7, rem = bi & 127, qt = rem >> 3, st = rem & 7;
  int t = threadIdx.x, w = t >> 6, l = t & 63, l15 = l & 15, quad = l >> 4;

  const float* asrow = As + ((b << 7) + st * 16 + l15) * 256;
  const float* aqrow[4];
#pragma unroll
  for (int mt = 0; mt < 4; mt++)
    aqrow[mt] = Aq + ((b << 8) + qt * 16 + w * 4 + mt) * 256;

  f32x4 acc[4][4] = {};
#pragma unroll
  for (int ko = 0; ko < 256; ko += 32) {
    int obase = ko + quad * 8;
    f32x4 a0v0 = *(const f32x4*)(a0c0 + obase);
    f32x4 a0v1 = *(const f32x4*)(a0c0 + obase + 4);
    f32x4 c0v0 = *(const f32x4*)(a0c0 + 256 + obase);
    f32x4 c0v1 = *(const f32x4*)(a0c0 + 256 + obase + 4);
    f32x4 as0 = *(const f32x4*)(asrow + obase);
    f32x4 as1 = *(const f32x4*)(asrow + obase + 4);

    s16x8 zh[4], zl[4];
#pragma unroll
    for (int mt = 0; mt < 4; mt++) {
      f32x4 aq0 = *(const f32x4*)(aqrow[mt] + obase);
      f32x4 aq1 = *(const f32x4*)(aqrow[mt] + obase + 4);
      f32x4 z0 = (aq0 + as0) * a0v0 + c0v0;
      f32x4 z1 = (aq1 + as1) * a0v1 + c0v1;
      s16x8 h, lo;
#pragma unroll
      for (int u = 0; u < 4; u++) {
        unsigned p0 = splitbf(fmaxf(z0[u], 0.0f));
        h[u] = (short)(p0 >> 16); lo[u] = (short)(p0 & 0xFFFFu);
        unsigned p1 = splitbf(fmaxf(z1[u], 0.0f));
        h[4 + u] = (short)(p1 >> 16); lo[4 + u] = (short)(p1 & 0xFFFFu);
      }
      zh[mt] = h; zl[mt] = lo;
    }
    s16x8 bh[4], bl[4];
#pragma unroll
    for (int nt = 0; nt < 4; nt++) {
      int off = (nt * 16 + l15) * 256 + obase;
      bh[nt] = *(const s16x8*)(W1h + off);
      bl[nt] = *(const s16x8*)(W1l + off);
    }
#pragma unroll
    for (int mt = 0; mt < 4; mt++)
#pragma unroll
      for (int nt = 0; nt < 4; nt++) {
        acc[mt][nt] = __builtin_amdgcn_mfma_f32_16x16x32_bf16(zh[mt], bh[nt], acc[mt][nt], 0, 0, 0);
        acc[mt][nt] = __builtin_amdgcn_mfma_f32_16x16x32_bf16(zl[mt], bh[nt], acc[mt][nt], 0, 0, 0);
        acc[mt][nt] = __builtin_amdgcn_mfma_f32_16x16x32_bf16(zh[mt], bl[nt], acc[mt][nt], 0, 0, 0);
      }
  }

  if (!PASS2) {
    // BN1 partial stats: per-lane sums over its 16 y1 values, j = nt*16+l15
    float bsum[4], bsq[4];
#pragma unroll
    for (int nt = 0; nt < 4; nt++) {
      float bias = b1[nt * 16 + l15];
      float s = 0, s2 = 0;
#pragma unroll
      for (int mt = 0; mt < 4; mt++)
#pragma unroll
        for (int r = 0; r < 4; r++) {
          float y = acc[mt][nt][r] + bias;
          s += y; s2 += y * y;
        }
      bsum[nt] = s; bsq[nt] = s2;
    }
    __shared__ float red[2][4][4][16];  // [sum|sq][wave][nt][l15]
#pragma unroll
    for (int nt = 0; nt < 4; nt++) {
      float s = bsum[nt], s2 = bsq[nt];
      s  += __shfl_xor(s, 16);  s  += __shfl_xor(s, 32);
      s2 += __shfl_xor(s2, 16); s2 += __shfl_xor(s2, 32);
      if (quad == 0) { red[0][w][nt][l15] = s; red[1][w][nt][l15] = s2; }
    }
    __syncthreads();
    if (t < 128) {
      int which = t >> 6, j = t & 63, nt = j >> 4, jl = j & 15;
      float v = red[which][0][nt][jl] + red[which][1][nt][jl] +
                red[which][2][nt][jl] + red[which][3][nt][jl];
      ws1p[bi * 128 + t] = v;  // t<64: sum over block, t>=64: sumsq
    }
  } else {
    float a1v[4], c1v[4], w2v[4], biasv[4];
#pragma unroll
    for (int nt = 0; nt < 4; nt++) {
      int j = nt * 16 + l15;
      a1v[nt] = a1c1[j]; c1v[nt] = a1c1[64 + j]; w2v[nt] = W2[j]; biasv[nt] = b1[j];
    }
    float b2v = b2[0];
    float ls = 0, ls2 = 0;
#pragma unroll
    for (int mt = 0; mt < 4; mt++) {
      float part[4] = {0, 0, 0, 0};
#pragma unroll
      for (int nt = 0; nt < 4; nt++)
#pragma unroll
        for (int r = 0; r < 4; r++) {
          float y = acc[mt][nt][r] + biasv[nt];
          float z = fmaxf(a1v[nt] * y + c1v[nt], 0.0f);
          part[r] += z * w2v[nt];
        }
#pragma unroll
      for (int r = 0; r < 4; r++) {
        float p = part[r];
        p += __shfl_xor(p, 1); p += __shfl_xor(p, 2);
        p += __shfl_xor(p, 4); p += __shfl_xor(p, 8);
        part[r] = p + b2v;
      }
      if (l15 == 0) {
        int q = qt * 16 + w * 4 + mt;
        int P = ((b * 256 + q) * 128) + st * 16 + quad * 4;
        f32x4 o;
#pragma unroll
        for (int r = 0; r < 4; r++) { o[r] = part[r]; ls += part[r]; ls2 += part[r] * part[r]; }
        *(f32x4*)(y2 + P) = o;
      }
    }
    __shared__ float rs[16], rs2[16];
    if (l15 == 0) { rs[t >> 4] = ls; rs2[t >> 4] = ls2; }
    __syncthreads();
    if (t == 0) {
      float s = 0, s2 = 0;
#pragma unroll
      for (int i = 0; i < 16; i++) { s += rs[i]; s2 += rs2[i]; }
      ws2p[bi * 2] = s; ws2p[bi * 2 + 1] = s2;
    }
  }
}

// ---------------------------------------------------------------------------
// K5: finalize BN1 -> a1[64], c1[64]
// ---------------------------------------------------------------------------
__global__ __launch_bounds__(512) void k_fin1(
    const float* __restrict__ ws1p, const float* __restrict__ g1,
    const float* __restrict__ bt1, float* __restrict__ a1c1)
{
  int t = threadIdx.x, idx = t & 127, part = t >> 7;
  float acc = 0;
  for (int blk = part; blk < 512; blk += 4) acc += ws1p[blk * 128 + idx];
  __shared__ float red[4][128];
  __shared__ float tot[128];
  red[part][idx] = acc;
  __syncthreads();
  if (t < 128) tot[t] = red[0][t] + red[1][t] + red[2][t] + red[3][t];
  __syncthreads();
  if (t < 64) {
    float mean = tot[t] * INV_N;
    float var = tot[64 + t] * INV_N - mean * mean;
    float a = g1[t] * rsqrtf(var + BN_EPS);
    a1c1[t] = a;
    a1c1[64 + t] = bt1[t] - mean * a;
  }
}

// ---------------------------------------------------------------------------
// K7: finalize BN2 -> a2, c2
// ---------------------------------------------------------------------------
__global__ __launch_bounds__(256) void k_fin2(
    const float* __restrict__ ws2p, const float* __restrict__ g2,
    const float* __restrict__ bt2, float* __restrict__ a2c2)
{
  int t = threadIdx.x;
  float s = 0, s2 = 0;
  for (int i = t; i < 512; i += 256) { s += ws2p[2 * i]; s2 += ws2p[2 * i + 1]; }
  __shared__ float rs[256], rs2[256];
  rs[t] = s; rs2[t] = s2;
  __syncthreads();
  for (int off = 128; off; off >>= 1) {
    if (t < off) { rs[t] += rs[t + off]; rs2[t] += rs2[t + off]; }
    __syncthreads();
  }
  if (t == 0) {
    float mean = rs[0] * INV_N;
    float var = rs2[0] * INV_N - mean * mean;
    float a = g2[0] * rsqrtf(var + BN_EPS);
    a2c2[0] = a;
    a2c2[1] = bt2[0] - mean * a;
  }
}

// ---------------------------------------------------------------------------
// K8: out[P] = relu(a2*y2[P] + c2); P order == [B,1,Q,S] flat; fp32 out
// ---------------------------------------------------------------------------
__global__ __launch_bounds__(256) void k_out(
    const float* __restrict__ y2, const float* __restrict__ a2c2, float* __restrict__ out)
{
  int i = blockIdx.x * 1024 + threadIdx.x * 4;
  float a = a2c2[0], c = a2c2[1];
  f32x4 v = *(const f32x4*)(y2 + i);
  f32x4 o;
#pragma unroll
  for (int r = 0; r < 4; r++) o[r] = fmaxf(a * v[r] + c, 0.0f);
  *(f32x4*)(out + i) = o;
}

extern "C" void kernel_launch(void* const* d_in, const int* in_sizes, int n_in,
                              void* d_out, int out_size, void* d_ws, size_t ws_size,
                              hipStream_t stream)
{
  const float* Sf  = (const float*)d_in[0];   // support [4,128,256]
  const float* Qf  = (const float*)d_in[1];   // query   [4,256,256]
  const float* W0  = (const float*)d_in[2];   // [256,512]
  const float* b0  = (const float*)d_in[3];
  const float* g0  = (const float*)d_in[4];
  const float* bt0 = (const float*)d_in[5];
  const float* W1  = (const float*)d_in[6];   // [64,256]
  const float* b1  = (const float*)d_in[7];
  const float* g1  = (const float*)d_in[8];
  const float* bt1 = (const float*)d_in[9];
  const float* W2  = (const float*)d_in[10];  // [1,64]
  const float* b2  = (const float*)d_in[11];
  const float* g2  = (const float*)d_in[12];
  const float* bt2 = (const float*)d_in[13];

  float* ws = (float*)d_ws;
  float*  Aq   = ws;                        // 262144 f
  float*  As   = ws + 262144;               // 131072 f
  float*  y2   = ws + 393216;               // 131072 f
  float*  ws0p = ws + 524288;               // 16384 f
  float*  a0c0 = ws + 540672;               // 512 f
  float*  ws1p = ws + 541184;               // 65536 f
  float*  a1c1 = ws + 606720;               // 128 f
  float*  ws2p = ws + 606848;               // 1024 f
  float*  a2c2 = ws + 607872;               // 2 f (+pad to 608000)
  ushort* W0h  = (ushort*)(ws + 608000);    // 131072 u16 = 65536 f
  ushort* W0l  = (ushort*)(ws + 673536);    // 131072 u16
  ushort* W1h  = (ushort*)(ws + 739072);    // 16384 u16 = 8192 f
  ushort* W1l  = (ushort*)(ws + 747264);    // 16384 u16  -> total 755456 f ~= 3.0 MB

  k_prep  <<<576, 256, 0, stream>>>(W0, W1, W0h, W0l, W1h, W1l);
  k_gemm0 <<<96, 64, 0, stream>>>(Qf, Sf, W0h, W0l, b0, Aq, As);
  k_stats0<<<16, 256, 0, stream>>>(Aq, As, ws0p);
  k_fin0  <<<1, 256, 0, stream>>>(ws0p, g0, bt0, a0c0);
  k_main_t<false><<<512, 256, 0, stream>>>(Aq, As, a0c0, W1h, W1l, b1, ws1p,
                                           a1c1, W2, b2, y2, ws2p);
  k_fin1  <<<1, 512, 0, stream>>>(ws1p, g1, bt1, a1c1);
  k_main_t<true> <<<512, 256, 0, stream>>>(Aq, As, a0c0, W1h, W1l, b1, ws1p,
                                           a1c1, W2, b2, y2, ws2p);
  k_fin2  <<<1, 256, 0, stream>>>(ws2p, g2, bt2, a2c2);
  k_out   <<<128, 256, 0, stream>>>(y2, a2c2, (float*)d_out);
}

// Round 4
// 189.000 us; speedup vs baseline: 1.0807x; 1.0807x over previous
//
#include <hip/hip_runtime.h>
#include <hip/hip_bf16.h>

// RelationNet fused pipeline, fp32 in/out, split-bf16 MFMA internal.
// B=4 Q=256 S=128 C=256; feats 512 -> 256 -> 64 -> 1; BN (training) + ReLU each layer.
//
// Factorization: concat(uq,us) @ W0^T = query@W0a^T + support@W0b^T
//   => Aq[b,q,o], As[b,s,o] (b0 folded into As). BN0 stats analytic:
//   sum  y0 = S*sum(Aq) + Q*sum(As)
//   sum y0^2 = S*sum(Aq^2) + Q*sum(As^2) + 2*sum_b (sum_q Aq[b])·(sum_s As[b])
// GEMM0 at ~fp32 accuracy: 3-term hi/lo bf16 split (ah·bh + al·bh + ah·bl).
// GEMM1 z-side bf16-RNE only (2^-9 rel), W1-side hi/lo split — fits error budget.

typedef __attribute__((ext_vector_type(4))) float f32x4;
typedef __attribute__((ext_vector_type(8))) short s16x8;
typedef __attribute__((ext_vector_type(4))) short s16x4;

#define BN_EPS 1e-5f
#define INV_N  (1.0f/131072.0f)

// pack two floats to bf16x2 (RNE) as a uint: low16 = bf16(a), high16 = bf16(b)
__device__ __forceinline__ unsigned pk_bf16(float a, float b) {
  float2 t; t.x = a; t.y = b;
  __hip_bfloat162 h = __float22bfloat162_rn(t);
  return *reinterpret_cast<unsigned*>(&h);
}

// RNE hi + exact-residual lo split of a pair
__device__ __forceinline__ void split2(float a, float b, unsigned& uh, unsigned& ul) {
  uh = pk_bf16(a, b);
  float ha = __uint_as_float(uh << 16);
  float hb = __uint_as_float(uh & 0xFFFF0000u);
  ul = pk_bf16(a - ha, b - hb);
}

// truncation split (for one-time weight prep)
__device__ __forceinline__ unsigned splitbf(float v) {
  unsigned u = __float_as_uint(v);
  unsigned hi = u >> 16;
  float r = v - __uint_as_float(u & 0xFFFF0000u);
  unsigned lo = __float_as_uint(r) >> 16;
  return (hi << 16) | lo;
}

union frag_u { s16x8 v; unsigned u[4]; };

// ---------------------------------------------------------------------------
// K0: pre-split W0 [256,512] and W1 [64,256] into hi/lo bf16 arrays.
// blocks 0..511 -> W0, 512..575 -> W1, block 576 -> zero ws0p (atomic accum).
// ---------------------------------------------------------------------------
__global__ __launch_bounds__(256) void k_prep(
    const float* __restrict__ W0, const float* __restrict__ W1,
    ushort* __restrict__ W0h, ushort* __restrict__ W0l,
    ushort* __restrict__ W1h, ushort* __restrict__ W1l,
    float* __restrict__ ws0p)
{
  int bi = blockIdx.x;
  if (bi == 576) {
    for (int i = 0; i < 16; i++) ws0p[i * 256 + threadIdx.x] = 0.0f;
    return;
  }
  const float* src; ushort *dh, *dl; int idx;
  if (bi < 512) { src = W0; dh = W0h; dl = W0l; idx = bi * 256 + threadIdx.x; }
  else          { src = W1; dh = W1h; dl = W1l; idx = (bi - 512) * 256 + threadIdx.x; }
  unsigned p = splitbf(src[idx]);
  dh[idx] = (ushort)(p >> 16); dl[idx] = (ushort)(p & 0xFFFFu);
}

// ---------------------------------------------------------------------------
// K1: Aq = query @ W0[:, :256]^T ; As = support @ W0[:, 256:]^T + b0
// 96 blocks x 256 thr = 384 waves; each wave one 16x64 tile (mtile = gw>>2,
// ntile = gw&3). gw<256: Aq (1024 rows); gw>=256: As (512 rows).
// Epilogue folds BN0 per-b partial stats via quad-shuffle + atomicAdd(ws0p):
// ws0p: [0:1024) sumAq[b][o], [1024:2048) sumsqAq, [2048:3072) sumAs, [3072:4096) sumsqAs
// ---------------------------------------------------------------------------
__global__ __launch_bounds__(256) void k_gemm0(
    const float* __restrict__ Qf, const float* __restrict__ Sf,
    const ushort* __restrict__ W0h, const ushort* __restrict__ W0l,
    const float* __restrict__ b0, float* __restrict__ Aq, float* __restrict__ As,
    float* __restrict__ ws0p)
{
  int gw = blockIdx.x * 4 + (threadIdx.x >> 6);
  int l = threadIdx.x & 63, l15 = l & 15, quad = l >> 4;
  int mtile = gw >> 2, ntile = gw & 3;
  bool isQ = (mtile < 64);
  const float* X;
  float* Out;
  int m0, koff, b;
  if (isQ) { m0 = mtile * 16; X = Qf; Out = Aq; koff = 0; b = m0 >> 8; }
  else     { m0 = (mtile - 64) * 16; X = Sf; Out = As; koff = 256; b = m0 >> 7; }
  int n0 = ntile * 64;

  f32x4 acc[4] = {};
#pragma unroll
  for (int ko = 0; ko < 256; ko += 32) {
    const float* row = X + (m0 + l15) * 256 + ko + quad * 8;
    f32x4 v0 = *(const f32x4*)(row);
    f32x4 v1 = *(const f32x4*)(row + 4);
    frag_u ah, al;
#pragma unroll
    for (int j = 0; j < 2; j++) {
      split2(v0[2 * j], v0[2 * j + 1], ah.u[j], al.u[j]);
      split2(v1[2 * j], v1[2 * j + 1], ah.u[2 + j], al.u[2 + j]);
    }
#pragma unroll
    for (int nt = 0; nt < 4; nt++) {
      int off = (n0 + nt * 16 + l15) * 512 + koff + ko + quad * 8;
      s16x8 bh = *(const s16x8*)(W0h + off);
      s16x8 bl = *(const s16x8*)(W0l + off);
      acc[nt] = __builtin_amdgcn_mfma_f32_16x16x32_bf16(ah.v, bh, acc[nt], 0, 0, 0);
      acc[nt] = __builtin_amdgcn_mfma_f32_16x16x32_bf16(al.v, bh, acc[nt], 0, 0, 0);
      acc[nt] = __builtin_amdgcn_mfma_f32_16x16x32_bf16(ah.v, bl, acc[nt], 0, 0, 0);
    }
  }
  // D: col = l15 (o-in-tile), row = quad*4 + r (X row in tile)
#pragma unroll
  for (int nt = 0; nt < 4; nt++) {
    int o = n0 + nt * 16 + l15;
    float bias = isQ ? 0.0f : b0[o];
    float cs = 0, cs2 = 0;
#pragma unroll
    for (int r = 0; r < 4; r++) {
      float y = acc[nt][r] + bias;
      Out[(m0 + quad * 4 + r) * 256 + o] = y;
      cs += y; cs2 += y * y;
    }
    cs  += __shfl_xor(cs, 16);  cs  += __shfl_xor(cs, 32);
    cs2 += __shfl_xor(cs2, 16); cs2 += __shfl_xor(cs2, 32);
    if (quad == 0) {
      int base = isQ ? 0 : 2048;
      atomicAdd(&ws0p[base + b * 256 + o], cs);
      atomicAdd(&ws0p[base + 1024 + b * 256 + o], cs2);
    }
  }
}

// ---------------------------------------------------------------------------
// K2: finalize BN0 -> a0[256], c0[256]  (z0 = relu(a0*(Aq+As) + c0))
// ---------------------------------------------------------------------------
__global__ __launch_bounds__(256) void k_fin0(
    const float* __restrict__ ws0p, const float* __restrict__ g0,
    const float* __restrict__ bt0, float* __restrict__ a0c0)
{
  int o = threadIdx.x;
  float sumY = 0, cross = 0, SQ2 = 0, SS2 = 0;
#pragma unroll
  for (int b = 0; b < 4; b++) {
    float sq1 = ws0p[b * 256 + o];
    float ss1 = ws0p[2048 + b * 256 + o];
    SQ2 += ws0p[1024 + b * 256 + o];
    SS2 += ws0p[3072 + b * 256 + o];
    sumY += 128.0f * sq1 + 256.0f * ss1;
    cross += sq1 * ss1;
  }
  float mean = sumY * INV_N;
  float sumY2 = 128.0f * SQ2 + 256.0f * SS2 + 2.0f * cross;
  float var = sumY2 * INV_N - mean * mean;
  float a = g0[o] * rsqrtf(var + BN_EPS);
  a0c0[o] = a;
  a0c0[256 + o] = bt0[o] - mean * a;
}

// ---------------------------------------------------------------------------
// K3/K5: main GEMM, two passes (recompute beats storing 32 MB of y1).
// Per (b, qtile, stile): z0 generated in bf16-RNE A-frag layout in regs,
// y1[16 q][16 s][64 j] = z0 @ W1^T + b1; W1 hi/lo split (2 MFMA per tile).
// PASS2=false: BN1 partial stats -> ws1p[bi][0:64)=sum,[64:128)=sumsq.
// PASS2=true : z1=relu(a1*y1+c1); y2 = z1@W2 + b2 (shuffle over 16 j-lanes),
//              y2 at true (b,q,s) order + BN2 partials ws2p.
// Mapping: q = qt*16 + w*4 + mt (uniform per tile); A-frag m(lane&15) = s;
// D: col(lane&15) = j-in-tile, row(quad*4+r) = s-in-tile.
// ---------------------------------------------------------------------------
template<bool PASS2>
__global__ __launch_bounds__(256) void k_main_t(
    const float* __restrict__ Aq, const float* __restrict__ As,
    const float* __restrict__ a0c0,
    const ushort* __restrict__ W1h, const ushort* __restrict__ W1l,
    const float* __restrict__ b1, float* __restrict__ ws1p,
    const float* __restrict__ a1c1, const float* __restrict__ W2,
    const float* __restrict__ b2, float* __restrict__ y2, float* __restrict__ ws2p)
{
  int bi = blockIdx.x;
  int b = bi >> 7, rem = bi & 127, qt = rem >> 3, st = rem & 7;
  int t = threadIdx.x, w = t >> 6, l = t & 63, l15 = l & 15, quad = l >> 4;

  const float* asrow = As + ((b << 7) + st * 16 + l15) * 256;
  const float* aqrow[4];
#pragma unroll
  for (int mt = 0; mt < 4; mt++)
    aqrow[mt] = Aq + ((b << 8) + qt * 16 + w * 4 + mt) * 256;

  f32x4 acc[4][4] = {};
#pragma unroll
  for (int ko = 0; ko < 256; ko += 32) {
    int obase = ko + quad * 8;
    f32x4 a0v0 = *(const f32x4*)(a0c0 + obase);
    f32x4 a0v1 = *(const f32x4*)(a0c0 + obase + 4);
    f32x4 c0v0 = *(const f32x4*)(a0c0 + 256 + obase);
    f32x4 c0v1 = *(const f32x4*)(a0c0 + 256 + obase + 4);
    f32x4 as0 = *(const f32x4*)(asrow + obase);
    f32x4 as1 = *(const f32x4*)(asrow + obase + 4);

    s16x8 zh[4];
#pragma unroll
    for (int mt = 0; mt < 4; mt++) {
      f32x4 aq0 = *(const f32x4*)(aqrow[mt] + obase);
      f32x4 aq1 = *(const f32x4*)(aqrow[mt] + obase + 4);
      f32x4 z0 = (aq0 + as0) * a0v0 + c0v0;
      f32x4 z1 = (aq1 + as1) * a0v1 + c0v1;
      frag_u zz;
      zz.u[0] = pk_bf16(fmaxf(z0[0], 0.0f), fmaxf(z0[1], 0.0f));
      zz.u[1] = pk_bf16(fmaxf(z0[2], 0.0f), fmaxf(z0[3], 0.0f));
      zz.u[2] = pk_bf16(fmaxf(z1[0], 0.0f), fmaxf(z1[1], 0.0f));
      zz.u[3] = pk_bf16(fmaxf(z1[2], 0.0f), fmaxf(z1[3], 0.0f));
      zh[mt] = zz.v;
    }
#pragma unroll
    for (int nt = 0; nt < 4; nt++) {
      int off = (nt * 16 + l15) * 256 + obase;
      s16x8 bh = *(const s16x8*)(W1h + off);
      s16x8 bl = *(const s16x8*)(W1l + off);
#pragma unroll
      for (int mt = 0; mt < 4; mt++) {
        acc[mt][nt] = __builtin_amdgcn_mfma_f32_16x16x32_bf16(zh[mt], bh, acc[mt][nt], 0, 0, 0);
        acc[mt][nt] = __builtin_amdgcn_mfma_f32_16x16x32_bf16(zh[mt], bl, acc[mt][nt], 0, 0, 0);
      }
    }
  }

  if (!PASS2) {
    float bsum[4], bsq[4];
#pragma unroll
    for (int nt = 0; nt < 4; nt++) {
      float bias = b1[nt * 16 + l15];
      float s = 0, s2 = 0;
#pragma unroll
      for (int mt = 0; mt < 4; mt++)
#pragma unroll
        for (int r = 0; r < 4; r++) {
          float y = acc[mt][nt][r] + bias;
          s += y; s2 += y * y;
        }
      bsum[nt] = s; bsq[nt] = s2;
    }
    __shared__ float red[2][4][4][16];  // [sum|sq][wave][nt][l15]
#pragma unroll
    for (int nt = 0; nt < 4; nt++) {
      float s = bsum[nt], s2 = bsq[nt];
      s  += __shfl_xor(s, 16);  s  += __shfl_xor(s, 32);
      s2 += __shfl_xor(s2, 16); s2 += __shfl_xor(s2, 32);
      if (quad == 0) { red[0][w][nt][l15] = s; red[1][w][nt][l15] = s2; }
    }
    __syncthreads();
    if (t < 128) {
      int which = t >> 6, j = t & 63, nt = j >> 4, jl = j & 15;
      float v = red[which][0][nt][jl] + red[which][1][nt][jl] +
                red[which][2][nt][jl] + red[which][3][nt][jl];
      ws1p[bi * 128 + t] = v;  // t<64: sum, t>=64: sumsq
    }
  } else {
    float a1v[4], c1v[4], w2v[4], biasv[4];
#pragma unroll
    for (int nt = 0; nt < 4; nt++) {
      int j = nt * 16 + l15;
      a1v[nt] = a1c1[j]; c1v[nt] = a1c1[64 + j]; w2v[nt] = W2[j]; biasv[nt] = b1[j];
    }
    float b2v = b2[0];
    float ls = 0, ls2 = 0;
#pragma unroll
    for (int mt = 0; mt < 4; mt++) {
      float part[4] = {0, 0, 0, 0};
#pragma unroll
      for (int nt = 0; nt < 4; nt++)
#pragma unroll
        for (int r = 0; r < 4; r++) {
          float y = acc[mt][nt][r] + biasv[nt];
          float z = fmaxf(a1v[nt] * y + c1v[nt], 0.0f);
          part[r] += z * w2v[nt];
        }
#pragma unroll
      for (int r = 0; r < 4; r++) {
        float p = part[r];
        p += __shfl_xor(p, 1); p += __shfl_xor(p, 2);
        p += __shfl_xor(p, 4); p += __shfl_xor(p, 8);
        part[r] = p + b2v;
      }
      if (l15 == 0) {
        int q = qt * 16 + w * 4 + mt;
        int P = ((b * 256 + q) * 128) + st * 16 + quad * 4;
        f32x4 o;
#pragma unroll
        for (int r = 0; r < 4; r++) { o[r] = part[r]; ls += part[r]; ls2 += part[r] * part[r]; }
        *(f32x4*)(y2 + P) = o;
      }
    }
    __shared__ float rs[16], rs2[16];
    if (l15 == 0) { rs[t >> 4] = ls; rs2[t >> 4] = ls2; }
    __syncthreads();
    if (t == 0) {
      float s = 0, s2 = 0;
#pragma unroll
      for (int i = 0; i < 16; i++) { s += rs[i]; s2 += rs2[i]; }
      ws2p[bi * 2] = s; ws2p[bi * 2 + 1] = s2;
    }
  }
}

// ---------------------------------------------------------------------------
// K4: finalize BN1 -> a1[64], c1[64]
// ---------------------------------------------------------------------------
__global__ __launch_bounds__(512) void k_fin1(
    const float* __restrict__ ws1p, const float* __restrict__ g1,
    const float* __restrict__ bt1, float* __restrict__ a1c1)
{
  int t = threadIdx.x, idx = t & 127, part = t >> 7;
  float acc = 0;
  for (int blk = part; blk < 512; blk += 4) acc += ws1p[blk * 128 + idx];
  __shared__ float red[4][128];
  __shared__ float tot[128];
  red[part][idx] = acc;
  __syncthreads();
  if (t < 128) tot[t] = red[0][t] + red[1][t] + red[2][t] + red[3][t];
  __syncthreads();
  if (t < 64) {
    float mean = tot[t] * INV_N;
    float var = tot[64 + t] * INV_N - mean * mean;
    float a = g1[t] * rsqrtf(var + BN_EPS);
    a1c1[t] = a;
    a1c1[64 + t] = bt1[t] - mean * a;
  }
}

// ---------------------------------------------------------------------------
// K6: finalize BN2 -> a2, c2
// ---------------------------------------------------------------------------
__global__ __launch_bounds__(256) void k_fin2(
    const float* __restrict__ ws2p, const float* __restrict__ g2,
    const float* __restrict__ bt2, float* __restrict__ a2c2)
{
  int t = threadIdx.x;
  float s = 0, s2 = 0;
  for (int i = t; i < 512; i += 256) { s += ws2p[2 * i]; s2 += ws2p[2 * i + 1]; }
  __shared__ float rs[256], rs2[256];
  rs[t] = s; rs2[t] = s2;
  __syncthreads();
  for (int off = 128; off; off >>= 1) {
    if (t < off) { rs[t] += rs[t + off]; rs2[t] += rs2[t + off]; }
    __syncthreads();
  }
  if (t == 0) {
    float mean = rs[0] * INV_N;
    float var = rs2[0] * INV_N - mean * mean;
    float a = g2[0] * rsqrtf(var + BN_EPS);
    a2c2[0] = a;
    a2c2[1] = bt2[0] - mean * a;
  }
}

// ---------------------------------------------------------------------------
// K7: out[P] = relu(a2*y2[P] + c2); P order == [B,1,Q,S] flat; fp32 out
// ---------------------------------------------------------------------------
__global__ __launch_bounds__(256) void k_out(
    const float* __restrict__ y2, const float* __restrict__ a2c2, float* __restrict__ out)
{
  int i = blockIdx.x * 1024 + threadIdx.x * 4;
  float a = a2c2[0], c = a2c2[1];
  f32x4 v = *(const f32x4*)(y2 + i);
  f32x4 o;
#pragma unroll
  for (int r = 0; r < 4; r++) o[r] = fmaxf(a * v[r] + c, 0.0f);
  *(f32x4*)(out + i) = o;
}

extern "C" void kernel_launch(void* const* d_in, const int* in_sizes, int n_in,
                              void* d_out, int out_size, void* d_ws, size_t ws_size,
                              hipStream_t stream)
{
  const float* Sf  = (const float*)d_in[0];   // support [4,128,256]
  const float* Qf  = (const float*)d_in[1];   // query   [4,256,256]
  const float* W0  = (const float*)d_in[2];   // [256,512]
  const float* b0  = (const float*)d_in[3];
  const float* g0  = (const float*)d_in[4];
  const float* bt0 = (const float*)d_in[5];
  const float* W1  = (const float*)d_in[6];   // [64,256]
  const float* b1  = (const float*)d_in[7];
  const float* g1  = (const float*)d_in[8];
  const float* bt1 = (const float*)d_in[9];
  const float* W2  = (const float*)d_in[10];  // [1,64]
  const float* b2  = (const float*)d_in[11];
  const float* g2  = (const float*)d_in[12];
  const float* bt2 = (const float*)d_in[13];

  float* ws = (float*)d_ws;
  float*  Aq   = ws;                        // 262144 f
  float*  As   = ws + 262144;               // 131072 f
  float*  y2   = ws + 393216;               // 131072 f
  float*  ws0p = ws + 524288;               // 4096 f (atomic accum, zeroed by k_prep)
  float*  a0c0 = ws + 528384;               // 512 f
  float*  ws1p = ws + 528896;               // 65536 f
  float*  a1c1 = ws + 594432;               // 128 f
  float*  ws2p = ws + 594560;               // 1024 f
  float*  a2c2 = ws + 595584;               // 2 f (pad to 595712)
  ushort* W0h  = (ushort*)(ws + 595712);    // 131072 u16 = 65536 f
  ushort* W0l  = (ushort*)(ws + 661248);    // 131072 u16
  ushort* W1h  = (ushort*)(ws + 726784);    // 16384 u16 = 8192 f
  ushort* W1l  = (ushort*)(ws + 734976);    // 16384 u16 -> total ~2.97 MB

  k_prep  <<<577, 256, 0, stream>>>(W0, W1, W0h, W0l, W1h, W1l, ws0p);
  k_gemm0 <<<96, 256, 0, stream>>>(Qf, Sf, W0h, W0l, b0, Aq, As, ws0p);
  k_fin0  <<<1, 256, 0, stream>>>(ws0p, g0, bt0, a0c0);
  k_main_t<false><<<512, 256, 0, stream>>>(Aq, As, a0c0, W1h, W1l, b1, ws1p,
                                           a1c1, W2, b2, y2, ws2p);
  k_fin1  <<<1, 512, 0, stream>>>(ws1p, g1, bt1, a1c1);
  k_main_t<true> <<<512, 256, 0, stream>>>(Aq, As, a0c0, W1h, W1l, b1, ws1p,
                                           a1c1, W2, b2, y2, ws2p);
  k_fin2  <<<1, 256, 0, stream>>>(ws2p, g2, bt2, a2c2);
  k_out   <<<128, 256, 0, stream>>>(y2, a2c2, (float*)d_out);
}